// Round 9
// baseline (228.098 us; speedup 1.0000x reference)
//
#include <hip/hip_runtime.h>

// ROI pooling 3D as one-hot MFMA GEMM (transposed): part[ch][seg] = sum_v feat[ch][v] * onehot[v][seg].
// Counts fused as row 128 via ones-vector GEMM (wave 0 only). No LDS, no atomics, deterministic tree.
// R9: GRID 1024->1280 + launch_bounds(256,5): 5 waves/SIMD for latency hiding (occupancy probe).
constexpr int SEG_N   = 95;
constexpr int CROP_D  = 91, CROP_H = 109, CROP_W = 91;
constexpr int LINES   = CROP_D * CROP_H;              // 9919
constexpr int FEAT_W  = 96;
constexpr int FEAT_HW = 112 * 96;
constexpr int CSTRIDE = 96 * 112 * 96;                // per-(b,c) elements
constexpr int NTILE   = LINES * 3;                    // 29757 tiles of 32 voxels (exact)
constexpr int PSEG    = 96;                           // 95 segs + trash col 95
constexpr int ROWS    = 129;                          // 128 ch + counts row
constexpr int BIN_SZ  = ROWS * PSEG;                  // 12384 floats per partial
constexpr int GRID    = 1280;                         // 5 blocks/CU
constexpr int NCHUNK  = 16;
constexpr int KPC     = GRID / NCHUNK;                // 80
constexpr int OUT_N   = 2 * 94 * 64;
constexpr size_t PART2_OFF = (size_t)GRID * BIN_SZ * sizeof(float);
constexpr size_t WS_NEED   = PART2_OFF + (size_t)NCHUNK * BIN_SZ * sizeof(float);

typedef __attribute__((ext_vector_type(8))) short bf16x8;
typedef __attribute__((ext_vector_type(4))) float f32x4;

__device__ inline unsigned int rne2(float a, float b) {   // 2x fp32 -> packed bf16 (RNE)
    unsigned int x = __float_as_uint(a), y = __float_as_uint(b);
    x = (x + 0x7FFFu + ((x >> 16) & 1u)) >> 16;
    y = (y + 0x7FFFu + ((y >> 16) & 1u)) & 0xFFFF0000u;
    return x | y;
}

__global__ __launch_bounds__(256) void zero_part(float* __restrict__ p)   // atomic-fallback only
{
    const int i = blockIdx.x * 256 + threadIdx.x;
    if (i < BIN_SZ) p[i] = 0.0f;
}

__global__ __launch_bounds__(256, 5) void seg_mfma(const float* __restrict__ feat,
                                                   const int*   __restrict__ atlas,
                                                   float* __restrict__ part,
                                                   int use_atomic)
{
    const int tid = threadIdx.x, wv = tid >> 6, lane = tid & 63;
    const int l15 = lane & 15, lq = lane >> 4;

    f32x4 acc[2][6];                                   // [ch-subtile][seg-tile]
    f32x4 accc[6];                                     // counts (live on wave 0 only)
    #pragma unroll
    for (int s = 0; s < 6; ++s) {
        acc[0][s] = (f32x4){0.f, 0.f, 0.f, 0.f};
        acc[1][s] = (f32x4){0.f, 0.f, 0.f, 0.f};
        accc[s]   = (f32x4){0.f, 0.f, 0.f, 0.f};
    }
    union { bf16x8 v; unsigned int u[4]; } ONES;
    ONES.u[0] = ONES.u[1] = ONES.u[2] = ONES.u[3] = 0x3F803F80u;

    // Contiguous balanced chunk per block.
    const int base = NTILE / GRID, rem = NTILE % GRID; // 23, 317
    const int bx   = blockIdx.x;
    const int t0   = bx * base + (bx < rem ? bx : rem);
    const int te   = t0 + base + (bx < rem ? 1 : 0);

    for (int t = t0; t < te; ++t) {
        const int line  = t / 3;                       // tile = 32 voxels inside one 96-wide line
        const int w0    = (t - line * 3) * 32;
        const int d     = line / CROP_H, h = line - d * CROP_H;
        const int lbase = d * FEAT_HW + h * FEAT_W + w0;

        // atlas ids for this lane's k-quarter: k = lq*8 + j (w >= 91 -> trash seg 95)
        int id[8];
        const int wq = w0 + lq * 8, abase = line * CROP_W + w0 + lq * 8;
        #pragma unroll
        for (int j = 0; j < 8; ++j)
            id[j] = (wq + j < CROP_W) ? atlas[abase + j] : 95;

        // B one-hot fragments per seg-tile: col = l15 (seg), k = lq*8 + j
        bf16x8 bv[6];
        #pragma unroll
        for (int sb = 0; sb < 6; ++sb) {
            const int seg = sb * 16 + l15;
            union { bf16x8 v; unsigned int u[4]; } B;
            #pragma unroll
            for (int p = 0; p < 4; ++p) {
                const unsigned int lo = (id[2 * p]     == seg) ? 0x3F80u     : 0u;
                const unsigned int hi = (id[2 * p + 1] == seg) ? 0x3F800000u : 0u;
                B.u[p] = lo | hi;
            }
            bv[sb] = B.v;
        }

        // counts: D = ones * onehot (all D rows identical = per-seg tile count)
        if (wv == 0) {
            #pragma unroll
            for (int sb = 0; sb < 6; ++sb)
                accc[sb] = __builtin_amdgcn_mfma_f32_16x16x32_bf16(ONES.v, bv[sb], accc[sb], 0, 0, 0);
        }

        // A fragments: row = l15 -> ch, k = lq*8 + j. One full 128B line per (ch, tile).
        #pragma unroll
        for (int a = 0; a < 2; ++a) {
            const int ch = wv * 32 + a * 16 + l15;
            const float* fp = feat + (size_t)ch * CSTRIDE + lbase + lq * 8;
            const float4 v0 = *(const float4*)fp;
            const float4 v1 = *(const float4*)(fp + 4);
            union { bf16x8 v; unsigned int u[4]; } A;
            A.u[0] = rne2(v0.x, v0.y); A.u[1] = rne2(v0.z, v0.w);
            A.u[2] = rne2(v1.x, v1.y); A.u[3] = rne2(v1.z, v1.w);
            #pragma unroll
            for (int sb = 0; sb < 6; ++sb)
                acc[a][sb] = __builtin_amdgcn_mfma_f32_16x16x32_bf16(A.v, bv[sb], acc[a][sb], 0, 0, 0);
        }
    }

    // Epilogue: D row = lq*4 + r (ch within 16), col = l15 (seg). Waves own disjoint rows.
    float* p = part + (use_atomic ? 0 : (size_t)blockIdx.x * BIN_SZ);
    #pragma unroll
    for (int a = 0; a < 2; ++a)
        #pragma unroll
        for (int sb = 0; sb < 6; ++sb)
            #pragma unroll
            for (int r = 0; r < 4; ++r) {
                const int i = (wv * 32 + a * 16 + lq * 4 + r) * PSEG + sb * 16 + l15;
                if (use_atomic) unsafeAtomicAdd(&p[i], acc[a][sb][r]);
                else            p[i] = acc[a][sb][r];
            }
    if (wv == 0 && lq == 0) {                          // counts row (any D row; take reg 0)
        #pragma unroll
        for (int sb = 0; sb < 6; ++sb) {
            const int i = 128 * PSEG + sb * 16 + l15;
            if (use_atomic) unsafeAtomicAdd(&p[i], accc[sb][0]);
            else            p[i] = accc[sb][0];
        }
    }
}

// Stage A: sum GRID partials down to NCHUNK, coalesced across elem.
__global__ __launch_bounds__(256) void reduce_stageA(const float* __restrict__ part,
                                                     float* __restrict__ part2)
{
    const int g = blockIdx.x * 256 + threadIdx.x;     // [0, BIN_SZ*NCHUNK)
    const int c = g / BIN_SZ, e = g - c * BIN_SZ;
    const float* p = part + (size_t)c * KPC * BIN_SZ + e;
    float s = 0.0f;
    #pragma unroll 8
    for (int k = 0; k < KPC; ++k) s += p[(size_t)k * BIN_SZ];
    part2[g] = s;
}

__global__ __launch_bounds__(256) void finalize(const float* __restrict__ src,
                                                float* __restrict__ out,
                                                int n)
{
    const int idx = blockIdx.x * 256 + threadIdx.x;
    if (idx >= OUT_N) return;
    const int c   = idx & 63;
    const int s0  = (idx >> 6) % 94;
    const int b   = idx / (94 * 64);
    const int seg = s0 + 1;
    const int ch  = b * 64 + c;
    float s = 0.0f, cnt = 0.0f;
    for (int k = 0; k < n; ++k) {
        s   += src[(size_t)k * BIN_SZ + ch * PSEG + seg];
        cnt += src[(size_t)k * BIN_SZ + 128 * PSEG + seg];
    }
    out[idx] = s / fmaxf(cnt, 1e-6f);
}

extern "C" void kernel_launch(void* const* d_in, const int* in_sizes, int n_in,
                              void* d_out, int out_size, void* d_ws, size_t ws_size,
                              hipStream_t stream)
{
    const float* feat  = (const float*)d_in[0];
    const int*   atlas = (const int*)d_in[1];
    float* out   = (float*)d_out;
    float* part  = (float*)d_ws;
    float* part2 = (float*)((char*)d_ws + PART2_OFF);
    const int use_atomic = (ws_size < WS_NEED) ? 1 : 0;

    if (use_atomic)
        zero_part<<<(BIN_SZ + 255) / 256, 256, 0, stream>>>(part);
    seg_mfma<<<GRID, 256, 0, stream>>>(feat, atlas, part, use_atomic);
    if (!use_atomic)
        reduce_stageA<<<(BIN_SZ * NCHUNK) / 256, 256, 0, stream>>>(part, part2);
    finalize<<<(OUT_N + 255) / 256, 256, 0, stream>>>(use_atomic ? part : part2, out,
                                                      use_atomic ? 1 : NCHUNK);
}

// Round 10
// 177.592 us; speedup vs baseline: 1.2844x; 1.2844x over previous
//
#include <hip/hip_runtime.h>

// ROI pooling 3D as one-hot MFMA GEMM (transposed): part[ch][seg] = sum_v feat[ch][v] * onehot[v][seg].
// R10: wave-private LDS staging. Loads are 512B-contiguous per channel stream (DRAM row locality);
// fragments read back from LDS in the R8-verified layout. No barriers (each wave reads only its
// own LDS slice). Counts fused as row 128 (wave 0). Deterministic reduction tree.
constexpr int CROP_D  = 91, CROP_H = 109, CROP_W = 91;
constexpr int FEAT_W  = 96;
constexpr int FEAT_HW = 112 * 96;
constexpr int CSTRIDE = 96 * 112 * 96;                // per-(b,c) elements
constexpr int PSEG    = 96;                           // 95 segs + trash col 95
constexpr int ROWS    = 129;                          // 128 ch + counts row
constexpr int BIN_SZ  = ROWS * PSEG;                  // 12384 floats per partial
constexpr int GRID    = 1024;                         // 4 blocks/CU
constexpr int NCHUNK  = 16;
constexpr int KPC     = GRID / NCHUNK;                // 64
constexpr int OUT_N   = 2 * 94 * 64;
constexpr int SPP     = 82;                           // super-tiles per plane: 81x4 tiles + 1x3
constexpr int NST     = CROP_D * SPP;                 // 7462 super-tiles
constexpr int ROWB    = 288;                          // LDS row stride bytes (conflict-free, 16B-aligned)
constexpr size_t PART2_OFF = (size_t)GRID * BIN_SZ * sizeof(float);
constexpr size_t WS_NEED   = PART2_OFF + (size_t)NCHUNK * BIN_SZ * sizeof(float);

typedef __attribute__((ext_vector_type(8))) short bf16x8;
typedef __attribute__((ext_vector_type(4))) float f32x4;

__device__ inline unsigned int rne2(float a, float b) {   // 2x fp32 -> packed bf16 (RNE)
    unsigned int x = __float_as_uint(a), y = __float_as_uint(b);
    x = (x + 0x7FFFu + ((x >> 16) & 1u)) >> 16;
    y = (y + 0x7FFFu + ((y >> 16) & 1u)) & 0xFFFF0000u;
    return x | y;
}

__global__ __launch_bounds__(256) void zero_part(float* __restrict__ p)   // atomic-fallback only
{
    const int i = blockIdx.x * 256 + threadIdx.x;
    if (i < BIN_SZ) p[i] = 0.0f;
}

__global__ __launch_bounds__(256, 4) void seg_mfma(const float* __restrict__ feat,
                                                   const int*   __restrict__ atlas,
                                                   float* __restrict__ part,
                                                   int use_atomic)
{
    __shared__ __align__(16) char lds[4 * 32 * ROWB];  // 36864 B; 4 wave-private slices
    const int tid = threadIdx.x, wv = tid >> 6, lane = tid & 63;
    const int l15 = lane & 15, lq = lane >> 4;          // fragment coords
    const int l5  = lane & 31, c2 = lane >> 5;          // staging coords
    char* slice = lds + wv * 32 * ROWB;

    f32x4 acc[2][6];                                    // [ch-subtile][seg-tile]
    f32x4 accc[6];                                      // counts (wave 0)
    #pragma unroll
    for (int s = 0; s < 6; ++s) {
        acc[0][s] = (f32x4){0.f, 0.f, 0.f, 0.f};
        acc[1][s] = (f32x4){0.f, 0.f, 0.f, 0.f};
        accc[s]   = (f32x4){0.f, 0.f, 0.f, 0.f};
    }
    union { bf16x8 v; unsigned int u[4]; } ONES;
    ONES.u[0] = ONES.u[1] = ONES.u[2] = ONES.u[3] = 0x3F803F80u;

    // Contiguous balanced chunk of super-tiles per block.
    const int base = NST / GRID, rem = NST % GRID;      // 7, 294
    const int bx   = blockIdx.x;
    const int st0  = bx * base + (bx < rem ? bx : rem);
    const int st1  = st0 + base + (bx < rem ? 1 : 0);

    for (int st = st0; st < st1; ++st) {
        const int d  = st / SPP, s = st - d * SPP;
        const int nt = (s < SPP - 1) ? 4 : 3;           // tiles in super-tile

        // ---- stage: 32 ch x 128 vox, 512B contiguous burst per channel stream ----
        // (tail overreads vox 96..127 into the plane's pad rows: in-bounds, never consumed)
        const float* fb = feat + (size_t)(wv * 32) * CSTRIDE + d * FEAT_HW + s * 128 + l5 * 4;
        #pragma unroll
        for (int g = 0; g < 4; ++g) {
            float4 pay[4];
            #pragma unroll
            for (int i = 0; i < 4; ++i)
                pay[i] = *(const float4*)(fb + (size_t)(g * 8 + i * 2 + c2) * CSTRIDE);
            #pragma unroll
            for (int i = 0; i < 4; ++i) {
                const int chl = g * 8 + i * 2 + c2;
                uint2 w; w.x = rne2(pay[i].x, pay[i].y); w.y = rne2(pay[i].z, pay[i].w);
                *(uint2*)(slice + chl * ROWB + l5 * 8) = w;   // vox l5*4.. as bf16
            }
        }

        // ---- compute: nt tiles of 32 voxels ----
        for (int ts = 0; ts < nt; ++ts) {
            const int tp = s * 4 + ts;                  // tile index within plane [0,327)
            const int h  = tp / 3, w0 = (tp - h * 3) * 32;
            const int wq = w0 + lq * 8;
            const int ab = (d * CROP_H + h) * CROP_W + wq;
            int id[8];
            #pragma unroll
            for (int j = 0; j < 8; ++j)
                id[j] = (wq + j < CROP_W) ? atlas[ab + j] : 95;

            bf16x8 bv[6];                               // one-hot B: col=l15 seg, k=lq*8+j
            #pragma unroll
            for (int sb = 0; sb < 6; ++sb) {
                const int seg = sb * 16 + l15;
                union { bf16x8 v; unsigned int u[4]; } B;
                #pragma unroll
                for (int p = 0; p < 4; ++p) {
                    const unsigned int lo = (id[2 * p]     == seg) ? 0x3F80u     : 0u;
                    const unsigned int hi = (id[2 * p + 1] == seg) ? 0x3F800000u : 0u;
                    B.u[p] = lo | hi;
                }
                bv[sb] = B.v;
            }

            if (wv == 0) {                              // counts: D = ones * onehot
                #pragma unroll
                for (int sb = 0; sb < 6; ++sb)
                    accc[sb] = __builtin_amdgcn_mfma_f32_16x16x32_bf16(ONES.v, bv[sb], accc[sb], 0, 0, 0);
            }

            // A from wave-private LDS: row=l15 ch, k=lq*8+j (voxel ts*32+lq*8+j)
            #pragma unroll
            for (int a = 0; a < 2; ++a) {
                const bf16x8 av = *(const bf16x8*)(slice + (a * 16 + l15) * ROWB + ts * 64 + lq * 16);
                #pragma unroll
                for (int sb = 0; sb < 6; ++sb)
                    acc[a][sb] = __builtin_amdgcn_mfma_f32_16x16x32_bf16(av, bv[sb], acc[a][sb], 0, 0, 0);
            }
        }
    }

    // Epilogue: D row = lq*4 + r (ch within 16), col = l15 (seg). Waves own disjoint rows.
    float* p = part + (use_atomic ? 0 : (size_t)blockIdx.x * BIN_SZ);
    #pragma unroll
    for (int a = 0; a < 2; ++a)
        #pragma unroll
        for (int sb = 0; sb < 6; ++sb)
            #pragma unroll
            for (int r = 0; r < 4; ++r) {
                const int i = (wv * 32 + a * 16 + lq * 4 + r) * PSEG + sb * 16 + l15;
                if (use_atomic) unsafeAtomicAdd(&p[i], acc[a][sb][r]);
                else            p[i] = acc[a][sb][r];
            }
    if (wv == 0 && lq == 0) {                           // counts row
        #pragma unroll
        for (int sb = 0; sb < 6; ++sb) {
            const int i = 128 * PSEG + sb * 16 + l15;
            if (use_atomic) unsafeAtomicAdd(&p[i], accc[sb][0]);
            else            p[i] = accc[sb][0];
        }
    }
}

// Stage A: sum GRID partials down to NCHUNK, coalesced across elem.
__global__ __launch_bounds__(256) void reduce_stageA(const float* __restrict__ part,
                                                     float* __restrict__ part2)
{
    const int g = blockIdx.x * 256 + threadIdx.x;       // [0, BIN_SZ*NCHUNK)
    const int c = g / BIN_SZ, e = g - c * BIN_SZ;
    const float* p = part + (size_t)c * KPC * BIN_SZ + e;
    float s = 0.0f;
    #pragma unroll 8
    for (int k = 0; k < KPC; ++k) s += p[(size_t)k * BIN_SZ];
    part2[g] = s;
}

__global__ __launch_bounds__(256) void finalize(const float* __restrict__ src,
                                                float* __restrict__ out,
                                                int n)
{
    const int idx = blockIdx.x * 256 + threadIdx.x;
    if (idx >= OUT_N) return;
    const int c   = idx & 63;
    const int s0  = (idx >> 6) % 94;
    const int b   = idx / (94 * 64);
    const int seg = s0 + 1;
    const int ch  = b * 64 + c;
    float s = 0.0f, cnt = 0.0f;
    for (int k = 0; k < n; ++k) {
        s   += src[(size_t)k * BIN_SZ + ch * PSEG + seg];
        cnt += src[(size_t)k * BIN_SZ + 128 * PSEG + seg];
    }
    out[idx] = s / fmaxf(cnt, 1e-6f);
}

extern "C" void kernel_launch(void* const* d_in, const int* in_sizes, int n_in,
                              void* d_out, int out_size, void* d_ws, size_t ws_size,
                              hipStream_t stream)
{
    const float* feat  = (const float*)d_in[0];
    const int*   atlas = (const int*)d_in[1];
    float* out   = (float*)d_out;
    float* part  = (float*)d_ws;
    float* part2 = (float*)((char*)d_ws + PART2_OFF);
    const int use_atomic = (ws_size < WS_NEED) ? 1 : 0;

    if (use_atomic)
        zero_part<<<(BIN_SZ + 255) / 256, 256, 0, stream>>>(part);
    seg_mfma<<<GRID, 256, 0, stream>>>(feat, atlas, part, use_atomic);
    if (!use_atomic)
        reduce_stageA<<<(BIN_SZ * NCHUNK) / 256, 256, 0, stream>>>(part, part2);
    finalize<<<(OUT_N + 255) / 256, 256, 0, stream>>>(use_atomic ? part : part2, out,
                                                      use_atomic ? 1 : NCHUNK);
}